// Round 9
// baseline (250.383 us; speedup 1.0000x reference)
//
#include <hip/hip_runtime.h>
#include <hip/hip_bf16.h>

#define T_SEQ 2048
#define DIMD  1024
#define INNER 2048
#define STATE 64
#define BATCH 4
#define NCHUNK 64
#define CHUNK_L (T_SEQ / NCHUNK)   // 32
#define MROWS (BATCH * T_SEQ)      // 8192
#define PSTRIDE ((long)MROWS * STATE)

typedef __hip_bfloat16 bf16;
typedef __attribute__((ext_vector_type(8))) short bf16x8v;
typedef __attribute__((ext_vector_type(4))) float f32x4v;
typedef __attribute__((ext_vector_type(4))) short short4v;

__device__ __forceinline__ float b2f(short s) {
    unsigned u = ((unsigned)(unsigned short)s) << 16;
    float f;
    __builtin_memcpy(&f, &u, 4);
    return f;
}
__device__ __forceinline__ short f2b(float f) {
    bf16 h = __float2bfloat16(f);  // RNE
    short s;
    __builtin_memcpy(&s, &h, 2);
    return s;
}

// async global->LDS, 16B per lane. LDS dest must be lane-linear.
__device__ __forceinline__ void gld_lds16(void* lds, const void* gsrc) {
    __builtin_amdgcn_global_load_lds(
        (const __attribute__((address_space(1))) unsigned*)gsrc,
        (__attribute__((address_space(3))) unsigned*)lds, 16, 0, 0);
}

template<int N> __device__ __forceinline__ void waitcnt_vm() {
    if constexpr (N == 8)      asm volatile("s_waitcnt vmcnt(8)" ::: "memory");
    else if constexpr (N == 4) asm volatile("s_waitcnt vmcnt(4)" ::: "memory");
    else                       asm volatile("s_waitcnt vmcnt(0)" ::: "memory");
}
__device__ __forceinline__ void block_barrier() {
    asm volatile("" ::: "memory");
    __builtin_amdgcn_s_barrier();
    asm volatile("" ::: "memory");
}

// ---------------------------------------------------------------------------
// NT GEMM, ring-2 double-buffer with COUNTED vmcnt (verified round 7):
//   iter t: stage(t+1)->buf[(t+1)&1]; vmcnt(LPS); barrier; compute(buf[t&1]);
//           barrier.
// Staging always targets the buffer NOT being read this iteration; the
// closing barrier fences re-staging of the read buffer -> race-free by
// construction (no cross-iteration half-tile staggering needed).
// PHASED (T3-lite + T5, round 9): compute split into 4 quadrant-phases
//   p = (mh, kkh): read 4 A-frags (+4 B-frags in p0/p1, reg-held), then
//   setprio(1); 16 MFMA; setprio(0); barrier + sched_barrier(0).
//   Mechanism: re-converged small phases let the 2 waves/SIMD offset
//   (one reads LDS while the other owns the MFMA pipe) — T5's prereq.
// XOR-swizzle (rule 21): linear LDS dest, pre-swizzled global source slot,
// same XOR on ds_read (row&7 == lane&7) -> zero bank conflicts (round 6).
// XSWZ: T1 bijective XCD block swizzle (requires nwg % 8 == 0).
// EPI: 0 = store bf16, 1 = store f32 (+split-K partial),
//      2 = fused y=acc+D*u, yg=y*silu(gate), store bf16 (u_ptr, gate_ptr, Dp)
//      3 = fused residual: store bf16(acc + x[row*N+col])  (x via u_ptr)
// MFMA 16x16x32 bf16 layouts (guide-verified m89/m91).
// ---------------------------------------------------------------------------
template<int BM, int BN, int BK, int WR, int WC, int EPI, int SPLITK, int XSWZ,
         int PHASED>
__global__ __launch_bounds__(WR*WC*64, 2)
void gemm_ring(const short* __restrict__ A, const short* __restrict__ B,
               void* __restrict__ Cout, int M, int N, int K,
               const short* __restrict__ u_ptr, const short* __restrict__ gate_ptr,
               const float* __restrict__ Dp)
{
    constexpr int MFR = BM / (WR * 16);
    constexpr int NFR = BN / (WC * 16);
    constexpr int THREADS = WR * WC * 64;
    constexpr int UPR = BK / 8;                 // 16B slots per LDS row (8)
    constexpr int AISS = (BM * UPR) / THREADS;
    constexpr int BISS = (BN * UPR) / THREADS;
    constexpr int LPS  = AISS + BISS;           // loads per stage per thread
    __shared__ __align__(16) short As[2][BM * BK];
    __shared__ __align__(16) short Bs[2][BN * BK];

    int bx = blockIdx.x, by = blockIdx.y;
    if constexpr (XSWZ) {                       // T1: contiguous chunk per XCD
        const int gx = gridDim.x;
        const int nwg = gx * gridDim.y;
        int id = by * gx + bx;
        const int cpx = nwg >> 3;               // nwg % 8 == 0 (launch invariant)
        id = (id & 7) * cpx + (id >> 3);
        bx = id % gx; by = id / gx;
    }

    const int tid  = threadIdx.x;
    const int lane = tid & 63;
    const int wave = tid >> 6;
    const int wm = (wave / WC) * (MFR * 16);
    const int wn = (wave % WC) * (NFR * 16);
    const long bm = (long)by * BM;
    const long bn = (long)bx * BN;

    f32x4v acc[MFR][NFR];
#pragma unroll
    for (int m = 0; m < MFR; m++)
#pragma unroll
        for (int n = 0; n < NFR; n++)
            acc[m][n] = (f32x4v){0.f, 0.f, 0.f, 0.f};

    const int rsel = lane & 15;
    const int ssrc = (((tid & 7) ^ ((tid >> 3) & 7)) * 8);  // pre-swizzled src slot
    const int swz  = lane & 7;                              // read-side XOR

    int kbeg = 0, kend = K;
    if constexpr (SPLITK > 1) {
        const int kch = K / SPLITK;
        kbeg = blockIdx.z * kch;
        kend = kbeg + kch;
    }
    const int nt = (kend - kbeg) / BK;

    auto stage = [&](int buf, int k0) {
#pragma unroll
        for (int i = 0; i < AISS; i++) {
            const int j = i * THREADS + tid;                // linear 16B slot
            gld_lds16(&As[buf][j * 8],
                      &A[(bm + (j >> 3)) * (long)K + k0 + ssrc]);
        }
#pragma unroll
        for (int i = 0; i < BISS; i++) {
            const int j = i * THREADS + tid;
            gld_lds16(&Bs[buf][j * 8],
                      &B[(bn + (j >> 3)) * (long)K + k0 + ssrc]);
        }
    };
    auto compute = [&](int buf) {
#pragma unroll
        for (int kk = 0; kk < BK; kk += 32) {
            const int slog = (kk >> 3) + (lane >> 4);       // logical slot
            const int soff = ((slog ^ swz) * 8);            // phys elem offset
            bf16x8v af[MFR], bfv[NFR];
#pragma unroll
            for (int m = 0; m < MFR; m++)
                af[m] = *(const bf16x8v*)&As[buf][(wm + m * 16 + rsel) * BK + soff];
#pragma unroll
            for (int n = 0; n < NFR; n++)
                bfv[n] = *(const bf16x8v*)&Bs[buf][(wn + n * 16 + rsel) * BK + soff];
#pragma unroll
            for (int m = 0; m < MFR; m++)
#pragma unroll
                for (int n = 0; n < NFR; n++)
                    acc[m][n] = __builtin_amdgcn_mfma_f32_16x16x32_bf16(
                        af[m], bfv[n], acc[m][n], 0, 0, 0);
        }
    };
    // 4 quadrant-phases: p = (mh = p>>1, kkh = p&1). B-frags reg-held.
    auto compute_phased = [&](int buf) {
        constexpr int MH = MFR / 2;
        bf16x8v bfr[2][NFR];
#pragma unroll
        for (int p = 0; p < 4; ++p) {
            const int mh = p >> 1, kh = p & 1, kk = kh * 32;
            const int slog = (kk >> 3) + (lane >> 4);
            const int soff = ((slog ^ swz) * 8);
            if (p < 2) {
#pragma unroll
                for (int n = 0; n < NFR; n++)
                    bfr[kh][n] = *(const bf16x8v*)&Bs[buf][(wn + n * 16 + rsel) * BK + soff];
            }
            bf16x8v af[MH];
#pragma unroll
            for (int m = 0; m < MH; m++)
                af[m] = *(const bf16x8v*)&As[buf][(wm + (mh * MH + m) * 16 + rsel) * BK + soff];
            __builtin_amdgcn_s_setprio(1);
#pragma unroll
            for (int m = 0; m < MH; m++)
#pragma unroll
                for (int n = 0; n < NFR; n++)
                    acc[mh * MH + m][n] = __builtin_amdgcn_mfma_f32_16x16x32_bf16(
                        af[m], bfr[kh][n], acc[mh * MH + m][n], 0, 0, 0);
            __builtin_amdgcn_s_setprio(0);
            if (p < 3) {
                block_barrier();
                __builtin_amdgcn_sched_barrier(0);
            }
        }
    };

    stage(0, kbeg);
    for (int t = 0; t < nt; ++t) {
        const bool pf = (t + 1 < nt);
        if (pf) stage((t + 1) & 1, kbeg + (t + 1) * BK);
        if (pf) waitcnt_vm<LPS>();
        else    waitcnt_vm<0>();
        block_barrier();
        if constexpr (PHASED) compute_phased(t & 1);
        else                  compute(t & 1);
        block_barrier();
    }

    float* fout = (float*)Cout;
    if constexpr (SPLITK > 1)
        fout += (long)blockIdx.z * (long)M * N;

#pragma unroll
    for (int m = 0; m < MFR; m++) {
#pragma unroll
        for (int n = 0; n < NFR; n++) {
            const long col  = bn + wn + n * 16 + (lane & 15);
            const long row0 = bm + wm + m * 16 + (lane >> 4) * 4;
#pragma unroll
            for (int j = 0; j < 4; j++) {
                const long row = row0 + j;
                const float v = acc[m][n][j];
                const long idx = row * (long)N + col;
                if constexpr (EPI == 0) {
                    ((short*)Cout)[idx] = f2b(v);
                } else if constexpr (EPI == 1) {
                    fout[idx] = v;
                } else if constexpr (EPI == 2) {
                    float uv = b2f(u_ptr[row * (long)INNER + col]);
                    float gv = b2f(gate_ptr[row * (long)(2 * INNER) + col]);
                    float yv = v + Dp[col] * uv;
                    float sg = gv / (1.f + __expf(-gv));
                    ((short*)Cout)[idx] = f2b(yv * sg);
                } else {   // EPI == 3: + residual x, store bf16
                    ((short*)Cout)[idx] = f2b(v + b2f(u_ptr[idx]));
                }
            }
        }
    }
}

// ---------------------------------------------------------------------------
// depthwise causal conv1d(k=4, left-pad 3) + bias + SiLU
// ---------------------------------------------------------------------------
__global__ __launch_bounds__(256)
void conv_silu_kernel(const short* __restrict__ xproj, const float* __restrict__ cw,
                      const float* __restrict__ cb, short* __restrict__ u)
{
    const int bt = blockIdx.x;
    const int t  = bt & (T_SEQ - 1);
    const int c0 = threadIdx.x * 8;

    float wreg[4][8];
#pragma unroll
    for (int i = 0; i < 8; i++) {
        float4 wv = *(const float4*)&cw[(c0 + i) * 4];
        wreg[0][i] = wv.x; wreg[1][i] = wv.y; wreg[2][i] = wv.z; wreg[3][i] = wv.w;
    }
    float acc[8];
#pragma unroll
    for (int i = 0; i < 8; i++) acc[i] = cb[c0 + i];

#pragma unroll
    for (int k = 0; k < 4; k++) {
        if (t - 3 + k < 0) continue;
        bf16x8v v = *(const bf16x8v*)&xproj[(long)(bt - 3 + k) * (2 * INNER) + c0];
#pragma unroll
        for (int i = 0; i < 8; i++) acc[i] += b2f(v[i]) * wreg[k][i];
    }
    short o[8];
#pragma unroll
    for (int i = 0; i < 8; i++) {
        float s = acc[i] / (1.f + __expf(-acc[i]));
        o[i] = f2b(s);
    }
    *(bf16x8v*)&u[(long)bt * INNER + c0] = *(const bf16x8v*)o;
}

// ---------------------------------------------------------------------------
// Chunked parallel scan; Bu given as 4 split-K partials (stride PSTRIDE)
// ---------------------------------------------------------------------------
__global__ __launch_bounds__(64)
void scan_local_kernel(const float* __restrict__ Bu, float* __restrict__ locfin)
{
    const int b  = blockIdx.x / NCHUNK;
    const int ch = blockIdx.x % NCHUNK;
    const long base = ((long)b * T_SEQ + (long)ch * CHUNK_L) * STATE + threadIdx.x;
    float h = 0.f;
#pragma unroll
    for (int t = 0; t < CHUNK_L; t++) {
        const long o = base + (long)t * STATE;
        float bu = (Bu[o] + Bu[o + PSTRIDE]) + (Bu[o + 2 * PSTRIDE] + Bu[o + 3 * PSTRIDE]);
        h = 0.95f * h + 0.05f * bu;
    }
    locfin[(long)blockIdx.x * STATE + threadIdx.x] = h;
}

__global__ __launch_bounds__(256)
void carry_kernel(const float* __restrict__ locfin, float* __restrict__ carry,
                  float decayL)
{
    __shared__ float sm[BATCH * NCHUNK * STATE];   // 64 KB
    for (int i = threadIdx.x; i < BATCH * NCHUNK * STATE; i += 256)
        sm[i] = locfin[i];
    __syncthreads();
    const int b = threadIdx.x >> 6, s = threadIdx.x & 63;
    float c = 0.f;
    for (int ch = 0; ch < NCHUNK; ch++) {
        const int idx = (b * NCHUNK + ch) * STATE + s;
        carry[idx] = c;
        c = decayL * c + sm[idx];
    }
}

__global__ __launch_bounds__(64)
void scan_apply_kernel(const float* __restrict__ Bu, const float* __restrict__ carry,
                       short* __restrict__ hs)
{
    const int b  = blockIdx.x / NCHUNK;
    const int ch = blockIdx.x % NCHUNK;
    const long base = ((long)b * T_SEQ + (long)ch * CHUNK_L) * STATE + threadIdx.x;
    float h = carry[(long)blockIdx.x * STATE + threadIdx.x];
#pragma unroll
    for (int t = 0; t < CHUNK_L; t++) {
        const long o = base + (long)t * STATE;
        float bu = (Bu[o] + Bu[o + PSTRIDE]) + (Bu[o + 2 * PSTRIDE] + Bu[o + 3 * PSTRIDE]);
        h = 0.95f * h + 0.05f * bu;
        hs[o] = f2b(h);
    }
}

// ---------------------------------------------------------------------------
// LayerNorm over pre-summed bf16 (y + x) -> out (f32)
// ---------------------------------------------------------------------------
__global__ __launch_bounds__(256)
void ln_kernel(const short* __restrict__ yx, const float* __restrict__ g,
               const float* __restrict__ b, float* __restrict__ out)
{
    const int row = blockIdx.x;
    const int c   = threadIdx.x * 4;
    const long off = (long)row * DIMD + c;
    const short4v yv = *(const short4v*)&yx[off];
    float s0 = b2f(yv[0]), s1 = b2f(yv[1]), s2 = b2f(yv[2]), s3 = b2f(yv[3]);
    float sum = s0 + s1 + s2 + s3;
    float sq  = s0 * s0 + s1 * s1 + s2 * s2 + s3 * s3;
#pragma unroll
    for (int o = 32; o > 0; o >>= 1) {
        sum += __shfl_down(sum, o);
        sq  += __shfl_down(sq, o);
    }
    __shared__ float rs[4], rq[4];
    const int wave = threadIdx.x >> 6, lane = threadIdx.x & 63;
    if (lane == 0) { rs[wave] = sum; rq[wave] = sq; }
    __syncthreads();
    float tsum = rs[0] + rs[1] + rs[2] + rs[3];
    float tsq  = rq[0] + rq[1] + rq[2] + rq[3];
    float mu  = tsum * (1.f / DIMD);
    float inv = rsqrtf(tsq * (1.f / DIMD) - mu * mu + 1e-5f);
    float4 gv = *(const float4*)&g[c];
    float4 bv = *(const float4*)&b[c];
    float4 ov;
    ov.x = (s0 - mu) * inv * gv.x + bv.x;
    ov.y = (s1 - mu) * inv * gv.y + bv.y;
    ov.z = (s2 - mu) * inv * gv.z + bv.z;
    ov.w = (s3 - mu) * inv * gv.w + bv.w;
    *(float4*)&out[off] = ov;
}

// ---------------------------------------------------------------------------
// fused f32->bf16 convert of all 5 tensors into the contiguous ws region
// ---------------------------------------------------------------------------
#define C4_X   2097152L                       // 8192*1024/4
#define C4_W1  (C4_X + 1048576L)              // + 4096*1024/4
#define C4_WB  (C4_W1 + 32768L)               // + 64*2048/4
#define C4_WC  (C4_WB + 32768L)               // + 2048*64/4
#define C4_TOT (C4_WC + 524288L)              // + 1024*2048/4 = 3,735,552

__global__ __launch_bounds__(256)
void cvt5_kernel(const float* __restrict__ x, const float* __restrict__ w1,
                 const float* __restrict__ wB, const float* __restrict__ wC,
                 const float* __restrict__ wO, short* __restrict__ dst)
{
    const long i = (long)blockIdx.x * 256 + threadIdx.x;
    if (i >= C4_TOT) return;
    const float* s;
    long off;
    if      (i < C4_X)  { s = x;  off = i; }
    else if (i < C4_W1) { s = w1; off = i - C4_X; }
    else if (i < C4_WB) { s = wB; off = i - C4_W1; }
    else if (i < C4_WC) { s = wC; off = i - C4_WB; }
    else                { s = wO; off = i - C4_WC; }
    float4 v = *(const float4*)&s[off * 4];
    short4v o = { f2b(v.x), f2b(v.y), f2b(v.z), f2b(v.w) };
    *(short4v*)&dst[i * 4] = o;
}

extern "C" void kernel_launch(void* const* d_in, const int* in_sizes, int n_in,
                              void* d_out, int out_size, void* d_ws, size_t ws_size,
                              hipStream_t stream)
{
    const float* x     = (const float*)d_in[0];
    const float* W_in  = (const float*)d_in[1];
    const float* cw    = (const float*)d_in[2];
    const float* cb    = (const float*)d_in[3];
    const float* W_B   = (const float*)d_in[4];
    const float* W_C   = (const float*)d_in[5];
    const float* Dp    = (const float*)d_in[6];
    const float* W_out = (const float*)d_in[7];
    const float* ln_g  = (const float*)d_in[8];
    const float* ln_b  = (const float*)d_in[9];

    // workspace layout (bytes). total: 133,693,440 (~128 MB)
    char* p = (char*)d_ws;
    short* xw    = (short*)(p);                 // x bf16 [8192,1024] — LIVE until GEMM4
    short* w1    = (short*)(p +  16777216);     // W_in bf16 — dead after GEMM1
    short* wB    = (short*)(p +  25165824);     // W_B bf16  — dead after GEMM2
    short* wC    = (short*)(p +  25427968);     // W_C bf16  — read by GEMM3
    short* wO    = (short*)(p +  25690112);     // W_out bf16 — read by GEMM4
    short* xproj = (short*)(p +  29884416);     // x_proj bf16 [8192,4096]
    short* u     = (short*)(p +  96993280);     // u bf16 [8192,2048]
    short* hs    = (short*)(p + 132644864);     // hs bf16 [8192,64]
    short* yg    = u;                           // alias: in-place GEMM3 epilogue
    short* yx    = xproj;                       // GEMM4 out bf16(y+x), over dead xproj
    // scan/split-K scratch in DEAD regions (xw must survive for GEMM4 EPI=3):
    float* BuP    = (float*)(p + 16777216);     // 4x [8192,64] f32 = 8,388,608 (w1)
    float* locfin = (float*)(p + 25165824);     // 65,536 (wB region, dead post-GEMM2)
    float* carry  = (float*)(p + 25231360);     // 65,536

    const int M = MROWS;  // 8192

    // one fused convert for x, W_in, W_B, W_C, W_out (contiguous dst)
    cvt5_kernel<<<(int)((C4_TOT + 255) / 256), 256, 0, stream>>>(
        x, W_in, W_B, W_C, W_out, xw);

    // GEMM1: x_proj = x @ W_in^T  [8192,4096] bf16 (256^2 ring-2, PHASED+T5)
    gemm_ring<256, 256, 64, 2, 4, 0, 1, 1, 1><<<dim3(2 * INNER / 256, M / 256), 512, 0, stream>>>(
        xw, w1, xproj, M, 2 * INNER, DIMD, nullptr, nullptr, nullptr);

    // conv + silu -> u
    conv_silu_kernel<<<M, 256, 0, stream>>>(xproj, cw, cb, u);

    // GEMM2: BuP[z] = u @ W_B^T partials  [4][8192, 64] f32 (split-K x4)
    gemm_ring<64, 64, 64, 2, 2, 1, 4, 0, 0><<<dim3(1, M / 64, 4), 256, 0, stream>>>(
        u, wB, BuP, M, STATE, INNER, nullptr, nullptr, nullptr);

    // chunked parallel scan -> hs (bf16); sums the 4 partials on load
    float decayL;
    {
        double dd = 1.0;
        for (int i = 0; i < CHUNK_L; i++) dd *= 0.95;
        decayL = (float)dd;
    }
    scan_local_kernel<<<BATCH * NCHUNK, STATE, 0, stream>>>(BuP, locfin);
    carry_kernel<<<1, 256, 0, stream>>>(locfin, carry, decayL);
    scan_apply_kernel<<<BATCH * NCHUNK, STATE, 0, stream>>>(BuP, carry, hs);

    // GEMM3: y = hs @ W_C^T ; yg = (y + D*u) * silu(gate)   [8192, 2048] bf16
    gemm_ring<128, 128, 64, 2, 2, 2, 1, 1, 0><<<dim3(INNER / 128, M / 128), 256, 0, stream>>>(
        hs, wC, yg, M, INNER, STATE, u, xproj + INNER, Dp);

    // GEMM4: yx = bf16(yg @ W_out^T + x)  [8192, 1024] (over dead xproj region)
    gemm_ring<128, 128, 64, 2, 2, 3, 1, 1, 0><<<dim3(DIMD / 128, M / 128), 256, 0, stream>>>(
        yg, wO, yx, M, DIMD, INNER, xw, nullptr, nullptr);

    // LayerNorm(yx) -> d_out
    ln_kernel<<<M, 256, 0, stream>>>(yx, ln_g, ln_b, (float*)d_out);
}

// Round 10
// 242.994 us; speedup vs baseline: 1.0304x; 1.0304x over previous
//
#include <hip/hip_runtime.h>
#include <hip/hip_bf16.h>

#define T_SEQ 2048
#define DIMD  1024
#define INNER 2048
#define STATE 64
#define BATCH 4
#define NCHUNK 64
#define CHUNK_L (T_SEQ / NCHUNK)   // 32
#define MROWS (BATCH * T_SEQ)      // 8192
#define PSTRIDE ((long)MROWS * STATE)

typedef __hip_bfloat16 bf16;
typedef __attribute__((ext_vector_type(8))) short bf16x8v;
typedef __attribute__((ext_vector_type(4))) float f32x4v;
typedef __attribute__((ext_vector_type(4))) short short4v;

__device__ __forceinline__ float b2f(short s) {
    unsigned u = ((unsigned)(unsigned short)s) << 16;
    float f;
    __builtin_memcpy(&f, &u, 4);
    return f;
}
__device__ __forceinline__ short f2b(float f) {
    bf16 h = __float2bfloat16(f);  // RNE
    short s;
    __builtin_memcpy(&s, &h, 2);
    return s;
}

// async global->LDS, 16B per lane. LDS dest must be lane-linear.
__device__ __forceinline__ void gld_lds16(void* lds, const void* gsrc) {
    __builtin_amdgcn_global_load_lds(
        (const __attribute__((address_space(1))) unsigned*)gsrc,
        (__attribute__((address_space(3))) unsigned*)lds, 16, 0, 0);
}

template<int N> __device__ __forceinline__ void waitcnt_vm() {
    if constexpr (N == 16)      asm volatile("s_waitcnt vmcnt(16)" ::: "memory");
    else if constexpr (N == 8)  asm volatile("s_waitcnt vmcnt(8)" ::: "memory");
    else if constexpr (N == 4)  asm volatile("s_waitcnt vmcnt(4)" ::: "memory");
    else                        asm volatile("s_waitcnt vmcnt(0)" ::: "memory");
}
__device__ __forceinline__ void block_barrier() {
    asm volatile("" ::: "memory");
    __builtin_amdgcn_s_barrier();
    asm volatile("" ::: "memory");
}

// ---------------------------------------------------------------------------
// 8-phase 256^2 GEMM (true m201-style port, ledger-verified).
// BM=BN=256, BK=64, 8 waves (512 thr). LDS: A[2 dbuf][2 half][128*64],
// B likewise = 128 KB. Per K-tile: 4 phases. Phase h computes BLOCK
// C-quadrant Q[h] of tile t (Q = (0,0),(1,0),(1,1),(0,1) in (Ahalf,Bhalf))
// with all 8 waves tiling the 128x128 quadrant as 2x4 (wave sub-tile 64x32,
// 16 MFMA/phase), and stages ONE half-tile of t+1 (order A0,B0,A1,B1) into
// dbuf[(t+1)&1]. Per-phase vmcnt(4)+barrier. Ledger (halves outstanding):
//   prologue: issue 0A0,0B0,0A1,0B1; vmcnt(4) -> 0A0,0B0 landed; barrier.
//   (t,0): reads tA0,tB0 (landed). issue (t+1)A0; vmcnt(4) retires tA1. bar.
//   (t,1): reads tA1,tB0.           issue (t+1)B0; vmcnt(4) retires tB1. bar.
//   (t,2): reads tA1,tB1.           issue (t+1)A1; vmcnt(4) retires (t+1)A0.
//   (t,3): reads tA0,tB1.           issue (t+1)B1; vmcnt(4) retires (t+1)B0.
//   -> (t+1,0) reads (t+1)A0,B0: both retired. Closes inductively.
// Staging writes dbuf[(t+1)&1], reads dbuf[t&1]: disjoint. vmcnt waits a
// load issued >=2 phases (~1600cy) earlier -> covers HBM latency.
// Rule 18: lgkmcnt(0) asm + sched_barrier(0) before the MFMA cluster.
// XOR swizzle identical to gemm_ring (zero conflicts, verified round 6).
// ---------------------------------------------------------------------------
template<int EPI, int XSWZ>
__global__ __launch_bounds__(512, 2)
void gemm_8ph(const short* __restrict__ A, const short* __restrict__ B,
              void* __restrict__ Cout, int M, int N, int K)
{
    __shared__ __align__(16) short As[2][2][128 * 64];
    __shared__ __align__(16) short Bs[2][2][128 * 64];

    int bx = blockIdx.x, by = blockIdx.y;
    if constexpr (XSWZ) {
        const int gx = gridDim.x;
        const int nwg = gx * gridDim.y;
        int id = by * gx + bx;
        const int cpx = nwg >> 3;
        id = (id & 7) * cpx + (id >> 3);
        bx = id % gx; by = id / gx;
    }

    const int tid  = threadIdx.x;
    const int lane = tid & 63;
    const int wave = tid >> 6;
    const int wm2 = (wave >> 2) & 1;        // 2 row-groups in a quadrant
    const int wn2 = wave & 3;               // 4 col-groups
    const long bm = (long)by * 256;
    const long bn = (long)bx * 256;

    const int rsel = lane & 15;
    const int ssrc = (((tid & 7) ^ ((tid >> 3) & 7)) * 8);
    const int swz  = lane & 7;

    f32x4v acc[4][4][2];                    // [quadrant][m][n]
#pragma unroll
    for (int q = 0; q < 4; q++)
#pragma unroll
        for (int m = 0; m < 4; m++)
#pragma unroll
            for (int n = 0; n < 2; n++)
                acc[q][m][n] = (f32x4v){0.f, 0.f, 0.f, 0.f};

    const int nt = K / 64;

    // stage half-tile h (0=A0,1=B0,2=A1,3=B1) of tile tt. 2 loads/thread.
    auto stage_half = [&](int tt, int h) {
        const int buf = tt & 1;
        const int half = h >> 1;
        const int k0 = tt * 64;
#pragma unroll
        for (int i = 0; i < 2; i++) {
            const int j = i * 512 + tid;    // slot in [128 rows][8 slots]
            if (h & 1)
                gld_lds16(&Bs[buf][half][j * 8],
                          &B[(bn + half * 128 + (j >> 3)) * (long)K + k0 + ssrc]);
            else
                gld_lds16(&As[buf][half][j * 8],
                          &A[(bm + half * 128 + (j >> 3)) * (long)K + k0 + ssrc]);
        }
    };

    // prologue: tile 0's 4 halves; guarantee A0,B0 before first phase
    stage_half(0, 0); stage_half(0, 1); stage_half(0, 2); stage_half(0, 3);
    waitcnt_vm<4>();
    block_barrier();

    for (int t = 0; t < nt; ++t) {
        const int buf = t & 1;
#pragma unroll
        for (int h = 0; h < 4; ++h) {
            const int QM[4] = {0, 1, 1, 0};
            const int QN[4] = {0, 0, 1, 1};
            const int qm = QM[h], qn = QN[h];
            // ds_read this phase's fragments (halves guaranteed by prev barrier)
            bf16x8v af[4][2], bfv[2][2];
#pragma unroll
            for (int kkh = 0; kkh < 2; kkh++) {
                const int slog = kkh * 4 + (lane >> 4);
                const int soff = ((slog ^ swz) * 8);
#pragma unroll
                for (int m = 0; m < 4; m++) {
                    const int ar = wm2 * 64 + m * 16 + rsel;
                    af[m][kkh] = *(const bf16x8v*)&As[buf][qm][ar * 64 + soff];
                }
#pragma unroll
                for (int n = 0; n < 2; n++) {
                    const int br = wn2 * 32 + n * 16 + rsel;
                    bfv[n][kkh] = *(const bf16x8v*)&Bs[buf][qn][br * 64 + soff];
                }
            }
            // stage one half-tile of t+1 into the other dbuf
            if (t + 1 < nt) {
                stage_half(t + 1, h);
                waitcnt_vm<4>();            // counted, never 0 in main loop
            } else if (h == 0) {
                waitcnt_vm<0>();            // final tile: drain once
            }
            asm volatile("s_waitcnt lgkmcnt(0)" ::: "memory");
            __builtin_amdgcn_sched_barrier(0);   // rule 18
            __builtin_amdgcn_s_setprio(1);
#pragma unroll
            for (int kkh = 0; kkh < 2; kkh++)
#pragma unroll
                for (int m = 0; m < 4; m++)
#pragma unroll
                    for (int n = 0; n < 2; n++)
                        acc[h][m][n] = __builtin_amdgcn_mfma_f32_16x16x32_bf16(
                            af[m][kkh], bfv[n][kkh], acc[h][m][n], 0, 0, 0);
            __builtin_amdgcn_s_setprio(0);
            block_barrier();
        }
    }

#pragma unroll
    for (int q = 0; q < 4; q++) {
        const int QM[4] = {0, 1, 1, 0};
        const int QN[4] = {0, 0, 1, 1};
#pragma unroll
        for (int m = 0; m < 4; m++) {
#pragma unroll
            for (int n = 0; n < 2; n++) {
                const long col  = bn + QN[q] * 128 + wn2 * 32 + n * 16 + (lane & 15);
                const long row0 = bm + QM[q] * 128 + wm2 * 64 + m * 16 + (lane >> 4) * 4;
#pragma unroll
                for (int j = 0; j < 4; j++) {
                    const long idx = (row0 + j) * (long)N + col;
                    ((short*)Cout)[idx] = f2b(acc[q][m][n][j]);
                }
            }
        }
    }
}

// ---------------------------------------------------------------------------
// NT GEMM, ring-2 double-buffer with COUNTED vmcnt (round-8 verified config)
// ---------------------------------------------------------------------------
template<int BM, int BN, int BK, int WR, int WC, int EPI, int SPLITK, int XSWZ>
__global__ __launch_bounds__(WR*WC*64, 2)
void gemm_ring(const short* __restrict__ A, const short* __restrict__ B,
               void* __restrict__ Cout, int M, int N, int K,
               const short* __restrict__ u_ptr, const short* __restrict__ gate_ptr,
               const float* __restrict__ Dp)
{
    constexpr int MFR = BM / (WR * 16);
    constexpr int NFR = BN / (WC * 16);
    constexpr int THREADS = WR * WC * 64;
    constexpr int UPR = BK / 8;
    constexpr int AISS = (BM * UPR) / THREADS;
    constexpr int BISS = (BN * UPR) / THREADS;
    constexpr int LPS  = AISS + BISS;
    __shared__ __align__(16) short As[2][BM * BK];
    __shared__ __align__(16) short Bs[2][BN * BK];

    int bx = blockIdx.x, by = blockIdx.y;
    if constexpr (XSWZ) {
        const int gx = gridDim.x;
        const int nwg = gx * gridDim.y;
        int id = by * gx + bx;
        const int cpx = nwg >> 3;
        id = (id & 7) * cpx + (id >> 3);
        bx = id % gx; by = id / gx;
    }

    const int tid  = threadIdx.x;
    const int lane = tid & 63;
    const int wave = tid >> 6;
    const int wm = (wave / WC) * (MFR * 16);
    const int wn = (wave % WC) * (NFR * 16);
    const long bm = (long)by * BM;
    const long bn = (long)bx * BN;

    f32x4v acc[MFR][NFR];
#pragma unroll
    for (int m = 0; m < MFR; m++)
#pragma unroll
        for (int n = 0; n < NFR; n++)
            acc[m][n] = (f32x4v){0.f, 0.f, 0.f, 0.f};

    const int rsel = lane & 15;
    const int ssrc = (((tid & 7) ^ ((tid >> 3) & 7)) * 8);
    const int swz  = lane & 7;

    int kbeg = 0, kend = K;
    if constexpr (SPLITK > 1) {
        const int kch = K / SPLITK;
        kbeg = blockIdx.z * kch;
        kend = kbeg + kch;
    }
    const int nt = (kend - kbeg) / BK;

    auto stage = [&](int buf, int k0) {
#pragma unroll
        for (int i = 0; i < AISS; i++) {
            const int j = i * THREADS + tid;
            gld_lds16(&As[buf][j * 8],
                      &A[(bm + (j >> 3)) * (long)K + k0 + ssrc]);
        }
#pragma unroll
        for (int i = 0; i < BISS; i++) {
            const int j = i * THREADS + tid;
            gld_lds16(&Bs[buf][j * 8],
                      &B[(bn + (j >> 3)) * (long)K + k0 + ssrc]);
        }
    };
    auto compute = [&](int buf) {
#pragma unroll
        for (int kk = 0; kk < BK; kk += 32) {
            const int slog = (kk >> 3) + (lane >> 4);
            const int soff = ((slog ^ swz) * 8);
            bf16x8v af[MFR], bfv[NFR];
#pragma unroll
            for (int m = 0; m < MFR; m++)
                af[m] = *(const bf16x8v*)&As[buf][(wm + m * 16 + rsel) * BK + soff];
#pragma unroll
            for (int n = 0; n < NFR; n++)
                bfv[n] = *(const bf16x8v*)&Bs[buf][(wn + n * 16 + rsel) * BK + soff];
#pragma unroll
            for (int m = 0; m < MFR; m++)
#pragma unroll
                for (int n = 0; n < NFR; n++)
                    acc[m][n] = __builtin_amdgcn_mfma_f32_16x16x32_bf16(
                        af[m], bfv[n], acc[m][n], 0, 0, 0);
        }
    };

    stage(0, kbeg);
    for (int t = 0; t < nt; ++t) {
        const bool pf = (t + 1 < nt);
        if (pf) stage((t + 1) & 1, kbeg + (t + 1) * BK);
        if (pf) waitcnt_vm<LPS>();
        else    waitcnt_vm<0>();
        block_barrier();
        compute(t & 1);
        block_barrier();
    }

    float* fout = (float*)Cout;
    if constexpr (SPLITK > 1)
        fout += (long)blockIdx.z * (long)M * N;

#pragma unroll
    for (int m = 0; m < MFR; m++) {
#pragma unroll
        for (int n = 0; n < NFR; n++) {
            const long col  = bn + wn + n * 16 + (lane & 15);
            const long row0 = bm + wm + m * 16 + (lane >> 4) * 4;
#pragma unroll
            for (int j = 0; j < 4; j++) {
                const long row = row0 + j;
                const float v = acc[m][n][j];
                const long idx = row * (long)N + col;
                if constexpr (EPI == 0) {
                    ((short*)Cout)[idx] = f2b(v);
                } else if constexpr (EPI == 1) {
                    fout[idx] = v;
                } else if constexpr (EPI == 2) {
                    float uv = b2f(u_ptr[row * (long)INNER + col]);
                    float gv = b2f(gate_ptr[row * (long)(2 * INNER) + col]);
                    float yv = v + Dp[col] * uv;
                    float sg = gv / (1.f + __expf(-gv));
                    ((short*)Cout)[idx] = f2b(yv * sg);
                } else {   // EPI == 3: + residual x, store bf16
                    ((short*)Cout)[idx] = f2b(v + b2f(u_ptr[idx]));
                }
            }
        }
    }
}

// ---------------------------------------------------------------------------
// depthwise causal conv1d(k=4, left-pad 3) + bias + SiLU
// ---------------------------------------------------------------------------
__global__ __launch_bounds__(256)
void conv_silu_kernel(const short* __restrict__ xproj, const float* __restrict__ cw,
                      const float* __restrict__ cb, short* __restrict__ u)
{
    const int bt = blockIdx.x;
    const int t  = bt & (T_SEQ - 1);
    const int c0 = threadIdx.x * 8;

    float wreg[4][8];
#pragma unroll
    for (int i = 0; i < 8; i++) {
        float4 wv = *(const float4*)&cw[(c0 + i) * 4];
        wreg[0][i] = wv.x; wreg[1][i] = wv.y; wreg[2][i] = wv.z; wreg[3][i] = wv.w;
    }
    float acc[8];
#pragma unroll
    for (int i = 0; i < 8; i++) acc[i] = cb[c0 + i];

#pragma unroll
    for (int k = 0; k < 4; k++) {
        if (t - 3 + k < 0) continue;
        bf16x8v v = *(const bf16x8v*)&xproj[(long)(bt - 3 + k) * (2 * INNER) + c0];
#pragma unroll
        for (int i = 0; i < 8; i++) acc[i] += b2f(v[i]) * wreg[k][i];
    }
    short o[8];
#pragma unroll
    for (int i = 0; i < 8; i++) {
        float s = acc[i] / (1.f + __expf(-acc[i]));
        o[i] = f2b(s);
    }
    *(bf16x8v*)&u[(long)bt * INNER + c0] = *(const bf16x8v*)o;
}

// ---------------------------------------------------------------------------
// Chunked parallel scan; Bu given as 4 split-K partials (stride PSTRIDE)
// ---------------------------------------------------------------------------
__global__ __launch_bounds__(64)
void scan_local_kernel(const float* __restrict__ Bu, float* __restrict__ locfin)
{
    const int b  = blockIdx.x / NCHUNK;
    const int ch = blockIdx.x % NCHUNK;
    const long base = ((long)b * T_SEQ + (long)ch * CHUNK_L) * STATE + threadIdx.x;
    float h = 0.f;
#pragma unroll
    for (int t = 0; t < CHUNK_L; t++) {
        const long o = base + (long)t * STATE;
        float bu = (Bu[o] + Bu[o + PSTRIDE]) + (Bu[o + 2 * PSTRIDE] + Bu[o + 3 * PSTRIDE]);
        h = 0.95f * h + 0.05f * bu;
    }
    locfin[(long)blockIdx.x * STATE + threadIdx.x] = h;
}

__global__ __launch_bounds__(256)
void carry_kernel(const float* __restrict__ locfin, float* __restrict__ carry,
                  float decayL)
{
    __shared__ float sm[BATCH * NCHUNK * STATE];   // 64 KB
    for (int i = threadIdx.x; i < BATCH * NCHUNK * STATE; i += 256)
        sm[i] = locfin[i];
    __syncthreads();
    const int b = threadIdx.x >> 6, s = threadIdx.x & 63;
    float c = 0.f;
    for (int ch = 0; ch < NCHUNK; ch++) {
        const int idx = (b * NCHUNK + ch) * STATE + s;
        carry[idx] = c;
        c = decayL * c + sm[idx];
    }
}

__global__ __launch_bounds__(64)
void scan_apply_kernel(const float* __restrict__ Bu, const float* __restrict__ carry,
                       short* __restrict__ hs)
{
    const int b  = blockIdx.x / NCHUNK;
    const int ch = blockIdx.x % NCHUNK;
    const long base = ((long)b * T_SEQ + (long)ch * CHUNK_L) * STATE + threadIdx.x;
    float h = carry[(long)blockIdx.x * STATE + threadIdx.x];
#pragma unroll
    for (int t = 0; t < CHUNK_L; t++) {
        const long o = base + (long)t * STATE;
        float bu = (Bu[o] + Bu[o + PSTRIDE]) + (Bu[o + 2 * PSTRIDE] + Bu[o + 3 * PSTRIDE]);
        h = 0.95f * h + 0.05f * bu;
        hs[o] = f2b(h);
    }
}

// ---------------------------------------------------------------------------
// LayerNorm over pre-summed bf16 (y + x) -> out (f32)
// ---------------------------------------------------------------------------
__global__ __launch_bounds__(256)
void ln_kernel(const short* __restrict__ yx, const float* __restrict__ g,
               const float* __restrict__ b, float* __restrict__ out)
{
    const int row = blockIdx.x;
    const int c   = threadIdx.x * 4;
    const long off = (long)row * DIMD + c;
    const short4v yv = *(const short4v*)&yx[off];
    float s0 = b2f(yv[0]), s1 = b2f(yv[1]), s2 = b2f(yv[2]), s3 = b2f(yv[3]);
    float sum = s0 + s1 + s2 + s3;
    float sq  = s0 * s0 + s1 * s1 + s2 * s2 + s3 * s3;
#pragma unroll
    for (int o = 32; o > 0; o >>= 1) {
        sum += __shfl_down(sum, o);
        sq  += __shfl_down(sq, o);
    }
    __shared__ float rs[4], rq[4];
    const int wave = threadIdx.x >> 6, lane = threadIdx.x & 63;
    if (lane == 0) { rs[wave] = sum; rq[wave] = sq; }
    __syncthreads();
    float tsum = rs[0] + rs[1] + rs[2] + rs[3];
    float tsq  = rq[0] + rq[1] + rq[2] + rq[3];
    float mu  = tsum * (1.f / DIMD);
    float inv = rsqrtf(tsq * (1.f / DIMD) - mu * mu + 1e-5f);
    float4 gv = *(const float4*)&g[c];
    float4 bv = *(const float4*)&b[c];
    float4 ov;
    ov.x = (s0 - mu) * inv * gv.x + bv.x;
    ov.y = (s1 - mu) * inv * gv.y + bv.y;
    ov.z = (s2 - mu) * inv * gv.z + bv.z;
    ov.w = (s3 - mu) * inv * gv.w + bv.w;
    *(float4*)&out[off] = ov;
}

// ---------------------------------------------------------------------------
// fused f32->bf16 convert of all 5 tensors into the contiguous ws region
// ---------------------------------------------------------------------------
#define C4_X   2097152L                       // 8192*1024/4
#define C4_W1  (C4_X + 1048576L)              // + 4096*1024/4
#define C4_WB  (C4_W1 + 32768L)               // + 64*2048/4
#define C4_WC  (C4_WB + 32768L)               // + 2048*64/4
#define C4_TOT (C4_WC + 524288L)              // + 1024*2048/4 = 3,735,552

__global__ __launch_bounds__(256)
void cvt5_kernel(const float* __restrict__ x, const float* __restrict__ w1,
                 const float* __restrict__ wB, const float* __restrict__ wC,
                 const float* __restrict__ wO, short* __restrict__ dst)
{
    const long i = (long)blockIdx.x * 256 + threadIdx.x;
    if (i >= C4_TOT) return;
    const float* s;
    long off;
    if      (i < C4_X)  { s = x;  off = i; }
    else if (i < C4_W1) { s = w1; off = i - C4_X; }
    else if (i < C4_WB) { s = wB; off = i - C4_W1; }
    else if (i < C4_WC) { s = wC; off = i - C4_WB; }
    else                { s = wO; off = i - C4_WC; }
    float4 v = *(const float4*)&s[off * 4];
    short4v o = { f2b(v.x), f2b(v.y), f2b(v.z), f2b(v.w) };
    *(short4v*)&dst[i * 4] = o;
}

extern "C" void kernel_launch(void* const* d_in, const int* in_sizes, int n_in,
                              void* d_out, int out_size, void* d_ws, size_t ws_size,
                              hipStream_t stream)
{
    const float* x     = (const float*)d_in[0];
    const float* W_in  = (const float*)d_in[1];
    const float* cw    = (const float*)d_in[2];
    const float* cb    = (const float*)d_in[3];
    const float* W_B   = (const float*)d_in[4];
    const float* W_C   = (const float*)d_in[5];
    const float* Dp    = (const float*)d_in[6];
    const float* W_out = (const float*)d_in[7];
    const float* ln_g  = (const float*)d_in[8];
    const float* ln_b  = (const float*)d_in[9];

    // workspace layout (bytes). total: 133,693,440 (~128 MB)
    char* p = (char*)d_ws;
    short* xw    = (short*)(p);                 // x bf16 [8192,1024] — LIVE until GEMM4
    short* w1    = (short*)(p +  16777216);     // W_in bf16 — dead after GEMM1
    short* wB    = (short*)(p +  25165824);     // W_B bf16  — dead after GEMM2
    short* wC    = (short*)(p +  25427968);     // W_C bf16  — read by GEMM3
    short* wO    = (short*)(p +  25690112);     // W_out bf16 — read by GEMM4
    short* xproj = (short*)(p +  29884416);     // x_proj bf16 [8192,4096]
    short* u     = (short*)(p +  96993280);     // u bf16 [8192,2048]
    short* hs    = (short*)(p + 132644864);     // hs bf16 [8192,64]
    short* yg    = u;                           // alias: in-place GEMM3 epilogue
    short* yx    = xproj;                       // GEMM4 out bf16(y+x), over dead xproj
    // scan/split-K scratch in DEAD regions (xw must survive for GEMM4 EPI=3):
    float* BuP    = (float*)(p + 16777216);     // 4x [8192,64] f32 = 8,388,608 (w1)
    float* locfin = (float*)(p + 25165824);     // 65,536 (wB region, dead post-GEMM2)
    float* carry  = (float*)(p + 25231360);     // 65,536

    const int M = MROWS;  // 8192

    // one fused convert for x, W_in, W_B, W_C, W_out (contiguous dst)
    cvt5_kernel<<<(int)((C4_TOT + 255) / 256), 256, 0, stream>>>(
        x, W_in, W_B, W_C, W_out, xw);

    // GEMM1: x_proj = x @ W_in^T  [8192,4096] bf16 — true 8-phase 256^2
    gemm_8ph<0, 1><<<dim3(2 * INNER / 256, M / 256), 512, 0, stream>>>(
        xw, w1, xproj, M, 2 * INNER, DIMD);

    // conv + silu -> u
    conv_silu_kernel<<<M, 256, 0, stream>>>(xproj, cw, cb, u);

    // GEMM2: BuP[z] = u @ W_B^T partials  [4][8192, 64] f32 (split-K x4)
    gemm_ring<64, 64, 64, 2, 2, 1, 4, 0><<<dim3(1, M / 64, 4), 256, 0, stream>>>(
        u, wB, BuP, M, STATE, INNER, nullptr, nullptr, nullptr);

    // chunked parallel scan -> hs (bf16); sums the 4 partials on load
    float decayL;
    {
        double dd = 1.0;
        for (int i = 0; i < CHUNK_L; i++) dd *= 0.95;
        decayL = (float)dd;
    }
    scan_local_kernel<<<BATCH * NCHUNK, STATE, 0, stream>>>(BuP, locfin);
    carry_kernel<<<1, 256, 0, stream>>>(locfin, carry, decayL);
    scan_apply_kernel<<<BATCH * NCHUNK, STATE, 0, stream>>>(BuP, carry, hs);

    // GEMM3: y = hs @ W_C^T ; yg = (y + D*u) * silu(gate)   [8192, 2048] bf16
    gemm_ring<128, 128, 64, 2, 2, 2, 1, 1><<<dim3(INNER / 128, M / 128), 256, 0, stream>>>(
        hs, wC, yg, M, INNER, STATE, u, xproj + INNER, Dp);

    // GEMM4: yx = bf16(yg @ W_out^T + x)  [8192, 1024] (over dead xproj region)
    gemm_ring<128, 128, 64, 2, 2, 3, 1, 1><<<dim3(DIMD / 128, M / 128), 256, 0, stream>>>(
        yg, wO, yx, M, DIMD, INNER, xw, nullptr, nullptr);

    // LayerNorm(yx) -> d_out
    ln_kernel<<<M, 256, 0, stream>>>(yx, ln_g, ln_b, (float*)d_out);
}